// Round 6
// baseline (991.123 us; speedup 1.0000x reference)
//
#include <hip/hip_runtime.h>
#include <hip/hip_bf16.h>

#define N_ATOMS 100000
#define N_RES   12500
#define N_EDGES 800000
#define D_IN    37
#define D       115
#define DP      128            // padded feature dim (bf16 row = 256 B)
#define MPAD    100096         // atoms padded to multiple of 128
#define N_LAYERS 4
#define SCE     1024           // elements per scan block (256 thr x 4)
#define NSCB    ((N_ATOMS + SCE - 1) / SCE)   // 98 scan blocks
#define KPROJ   64             // D_IN padded to MFMA K multiple
#define LSTRIDE 72             // proj LDS row stride (bf16)

typedef __bf16 bf16x8 __attribute__((ext_vector_type(8)));
typedef float  f32x4  __attribute__((ext_vector_type(4)));
typedef unsigned int u32x4 __attribute__((ext_vector_type(4)));

__device__ __forceinline__ unsigned short f2bf(float f) {
  unsigned u = __builtin_bit_cast(unsigned, f);
  u += 0x7fffu + ((u >> 16) & 1u);            // RNE
  return (unsigned short)(u >> 16);
}
__device__ __forceinline__ float bf2f(unsigned short h) {
  unsigned u = ((unsigned)h) << 16;
  return __builtin_bit_cast(float, u);
}
__device__ __forceinline__ bf16x8 ld_frag(const unsigned short* p) {
  u32x4 u = *reinterpret_cast<const u32x4*>(p);
  return __builtin_bit_cast(bf16x8, u);
}

// ---- CSR build -------------------------------------------------------------
__global__ void k_hist_edges(const int* __restrict__ eidx, int* __restrict__ hist) {
  int e = blockIdx.x * blockDim.x + threadIdx.x;
  if (e < N_EDGES) atomicAdd(&hist[eidx[N_EDGES + e]], 1);
}

__global__ __launch_bounds__(256) void k_scan_part(
    const int* __restrict__ cnt, int* __restrict__ bsum)
{
  __shared__ int sh[256];
  const int t = threadIdx.x, b = blockIdx.x;
  const int base = b * SCE + t * 4;
  int s = 0;
  #pragma unroll
  for (int i = 0; i < 4; ++i) { int id = base + i; if (id < N_ATOMS) s += cnt[id]; }
  sh[t] = s; __syncthreads();
  for (int d = 128; d > 0; d >>= 1) { if (t < d) sh[t] += sh[t + d]; __syncthreads(); }
  if (t == 0) bsum[b] = sh[0];
}
__global__ __launch_bounds__(256) void k_scan_bsum(
    int* __restrict__ bsum, int* __restrict__ total)
{
  __shared__ int sh[256];
  const int t = threadIdx.x;
  int v = (t < NSCB) ? bsum[t] : 0;
  sh[t] = v; __syncthreads();
  for (int d = 1; d < 256; d <<= 1) {
    int u = (t >= d) ? sh[t - d] : 0;
    __syncthreads();
    sh[t] += u;
    __syncthreads();
  }
  if (t < NSCB) bsum[t] = sh[t] - v;          // exclusive
  if (t == 255) *total = sh[255];
}
__global__ __launch_bounds__(256) void k_scan_final(
    const int* __restrict__ cnt, const int* __restrict__ bsum,
    int* __restrict__ offs, int* __restrict__ cursor, float* __restrict__ invdeg)
{
  __shared__ int sh[256];
  const int t = threadIdx.x, b = blockIdx.x;
  const int base = b * SCE + t * 4;
  int c[4]; int s = 0;
  #pragma unroll
  for (int i = 0; i < 4; ++i) {
    int id = base + i;
    c[i] = (id < N_ATOMS) ? cnt[id] : 0;
    s += c[i];
  }
  sh[t] = s; __syncthreads();
  for (int d = 1; d < 256; d <<= 1) {
    int u = (t >= d) ? sh[t - d] : 0;
    __syncthreads();
    sh[t] += u;
    __syncthreads();
  }
  int run = bsum[b] + sh[t] - s;
  #pragma unroll
  for (int i = 0; i < 4; ++i) {
    int id = base + i;
    if (id < N_ATOMS) {
      offs[id] = run;
      cursor[id] = run;
      invdeg[id] = 1.0f / (float)max(c[i], 1);
      run += c[i];
    }
  }
}

__global__ __launch_bounds__(256) void k_res_bounds(
    const int* __restrict__ r2a, int* __restrict__ res_start)
{
  int r = blockIdx.x * blockDim.x + threadIdx.x;
  if (r > N_RES) return;
  int lo = 0, hi = N_ATOMS;
  while (lo < hi) {
    int mid = (lo + hi) >> 1;
    if (r2a[mid] < r) lo = mid + 1; else hi = mid;
  }
  res_start[r] = lo;
}

__global__ void k_fill(const int* __restrict__ eidx, int* __restrict__ cursor,
                       int* __restrict__ srcs) {
  int e = blockIdx.x * blockDim.x + threadIdx.x;
  if (e < N_EDGES) {
    int s = eidx[e], d = eidx[N_EDGES + e];
    int pos = atomicAdd(&cursor[d], 1);
    srcs[pos] = s;
  }
}

// ---- build augmented right-multipliers R[l][side][128][128] f32 ------------
// side 0 = Rl (A-path):  Rl[k][c] = Wl[l][c][k]            (const row/col = 0)
// side 1 = Rr (id-path): Rr[k][c] = Wr[l][c][k]; Rr[115][c]=bl[c]; Rr[115][115]=1
__global__ void k_buildR(const float* __restrict__ Wl, const float* __restrict__ Wr,
                         const float* __restrict__ bl, float* __restrict__ R)
{
  int idx = blockIdx.x * 256 + threadIdx.x;
  if (idx >= 4 * 2 * 128 * 128) return;
  int c = idx & 127, k = (idx >> 7) & 127, side = (idx >> 14) & 1, l = idx >> 15;
  float v = 0.f;
  if (side == 0) {
    if (k < D && c < D) v = Wl[(size_t)l * D * D + c * D + k];
  } else {
    if (k < D && c < D) v = Wr[(size_t)l * D * D + c * D + k];
    else if (k == D && c < D) v = bl[l * D + c];
    else if (k == D && c == D) v = 1.f;
  }
  R[idx] = v;
}

__global__ void k_ginit(float* __restrict__ G) {
  int idx = blockIdx.x * 256 + threadIdx.x;
  if (idx < 16384) G[idx] = ((idx >> 7) == (idx & 127)) ? 1.f : 0.f;
}

// ---- DP: G_k(l) = G_k(l-1) @ Rr_l + G_{k-1}(l-1) @ Rl_l --------------------
// grid = (lmax+1)*4 blocks; block b: k = b>>2, rows (b&3)*32..+32
__global__ __launch_bounds__(256) void k_mdp(
    const float* __restrict__ Gp, float* __restrict__ Gn,
    const float* __restrict__ Rl, const float* __restrict__ Rr, int lmax)
{
  const int b = blockIdx.x;
  const int k = b >> 2;
  const int r = (b & 3) * 32 + (threadIdx.x >> 3);
  const int c0 = (threadIdx.x & 7) * 16;
  float acc[16];
  #pragma unroll
  for (int q = 0; q < 16; ++q) acc[q] = 0.f;
  if (k <= lmax - 1) {
    const float* g = Gp + (size_t)k * 16384 + r * 128;
    for (int j = 0; j < 128; ++j) {
      const float a = g[j];
      const float* rr = Rr + j * 128 + c0;
      #pragma unroll
      for (int q = 0; q < 16; ++q) acc[q] += a * rr[q];
    }
  }
  if (k >= 1) {
    const float* g = Gp + (size_t)(k - 1) * 16384 + r * 128;
    for (int j = 0; j < 128; ++j) {
      const float a = g[j];
      const float* rl = Rl + j * 128 + c0;
      #pragma unroll
      for (int q = 0; q < 16; ++q) acc[q] += a * rl[q];
    }
  }
  float* o = Gn + (size_t)k * 16384 + r * 128 + c0;
  #pragma unroll
  for (int q = 0; q < 16; ++q) o[q] = acc[q];
}

// ---- input projection via MFMA: y0 = A @ lnW^T + lnb, bf16 [MPAD][128] -----
// col 115 = constant 1.0 (bias carrier), cols 116..127 = 0
__global__ __launch_bounds__(256) void k_proj(
    const float* __restrict__ A, const float* __restrict__ Wf,
    const float* __restrict__ bf, unsigned short* __restrict__ xout)
{
  __shared__ unsigned short sA[128 * LSTRIDE];
  __shared__ unsigned short sW[128 * LSTRIDE];
  const int t = threadIdx.x;
  const int r0 = blockIdx.x * 128;

  for (int idx = t; idx < 128 * KPROJ; idx += 256) {
    const int row = idx >> 6, k = idx & 63;
    const int gr = r0 + row;
    unsigned short v = 0;
    if (k < D_IN && gr < N_ATOMS) v = f2bf(A[(size_t)gr * D_IN + k]);
    sA[row * LSTRIDE + k] = v;
  }
  for (int idx = t; idx < 128 * KPROJ; idx += 256) {
    const int col = idx >> 6, k = idx & 63;
    unsigned short v = 0;
    if (col < D && k < D_IN) v = f2bf(Wf[col * D_IN + k]);
    sW[col * LSTRIDE + k] = v;
  }
  __syncthreads();

  const int lane = t & 63;
  const int wid  = t >> 6;
  const int wrow = wid * 32;
  const int lrow = lane & 15;
  const int koff = (lane >> 4) * 8;

  f32x4 acc[2][8];
  #pragma unroll
  for (int i = 0; i < 2; ++i)
    #pragma unroll
    for (int j = 0; j < 8; ++j)
      acc[i][j] = (f32x4){0.f, 0.f, 0.f, 0.f};

  #pragma unroll
  for (int ks = 0; ks < 2; ++ks) {
    const int k0 = ks * 32 + koff;
    bf16x8 a0 = ld_frag(&sA[(wrow + lrow) * LSTRIDE + k0]);
    bf16x8 a1 = ld_frag(&sA[(wrow + 16 + lrow) * LSTRIDE + k0]);
    #pragma unroll
    for (int ct = 0; ct < 8; ++ct) {
      bf16x8 b = ld_frag(&sW[(ct * 16 + lrow) * LSTRIDE + k0]);
      acc[0][ct] = __builtin_amdgcn_mfma_f32_16x16x32_bf16(a0, b, acc[0][ct], 0, 0, 0);
      acc[1][ct] = __builtin_amdgcn_mfma_f32_16x16x32_bf16(a1, b, acc[1][ct], 0, 0, 0);
    }
  }

  const int ocol = lane & 15;
  const int orow = (lane >> 4) * 4;
  #pragma unroll
  for (int ct = 0; ct < 8; ++ct) {
    const int col = ct * 16 + ocol;
    const float bv = (col < D) ? bf[col] : 0.f;
    #pragma unroll
    for (int rt = 0; rt < 2; ++rt) {
      #pragma unroll
      for (int j = 0; j < 4; ++j) {
        const int grow = r0 + wrow + rt * 16 + orow + j;
        if (grow < N_ATOMS) {
          unsigned short ov = (col == D) ? (unsigned short)0x3F80
                                         : f2bf(acc[rt][ct][j] + bv);
          xout[(size_t)grow * DP + col] = ov;
        }
      }
    }
  }
}

// ---- CSR mean aggregation: one wave per node, batched-ILP gather -----------
__global__ __launch_bounds__(256) void k_agg(
    const unsigned int* __restrict__ xin, const int* __restrict__ row_start,
    const int* __restrict__ srcs, const float* __restrict__ invdeg,
    unsigned int* __restrict__ aggout)
{
  const int w = (int)((blockIdx.x * 256 + threadIdx.x) >> 6);
  const int lane = threadIdx.x & 63;
  if (w >= N_ATOMS) return;
  const int beg = row_start[w], end = row_start[w + 1];
  float a0 = 0.f, a1 = 0.f;
  for (int base = beg; base < end; base += 16) {
    const int m = end - base;                  // >=1
    int sidx = 0;
    if (lane < 16 && lane < m) sidx = srcs[base + lane];
    #pragma unroll
    for (int j = 0; j < 16; ++j) {
      const int s = __shfl(sidx, j);
      const unsigned int v = xin[(size_t)s * 64 + lane];  // independent loads
      if (j < m) {
        a0 += bf2f((unsigned short)(v & 0xffffu));
        a1 += bf2f((unsigned short)(v >> 16));
      }
    }
  }
  const float sc = invdeg[w];
  unsigned int o = (unsigned int)f2bf(a0 * sc) | ((unsigned int)f2bf(a1 * sc) << 16);
  aggout[w * 64 + lane] = o;
}

// ---- pooling into pstack slice: f32 [N_RES][128] ---------------------------
__global__ __launch_bounds__(256) void k_pool128(
    const unsigned int* __restrict__ x, const int* __restrict__ res_start,
    float* __restrict__ outp)
{
  const int r = (int)((blockIdx.x * 256 + threadIdx.x) >> 6);
  const int lane = threadIdx.x & 63;
  if (r >= N_RES) return;
  const int beg = res_start[r], end = res_start[r + 1];
  float a0 = 0.f, a1 = 0.f;
  for (int a = beg; a < end; ++a) {
    unsigned int v = x[(size_t)a * 64 + lane];
    a0 += bf2f((unsigned short)(v & 0xffffu));
    a1 += bf2f((unsigned short)(v >> 16));
  }
  outp[(size_t)r * 128 + lane * 2]     = a0;
  outp[(size_t)r * 128 + lane * 2 + 1] = a1;
}

// ---- final: out[r][c] = sum_k sum_j pstack[k][r][j] * G[k][j][c], c<115 ----
__global__ __launch_bounds__(256) void k_final(
    const float* __restrict__ pstack, const float* __restrict__ G,
    float* __restrict__ out)
{
  const int r = blockIdx.x * 2 + (threadIdx.x >> 7);
  const int c = threadIdx.x & 127;
  if (r >= N_RES) return;
  float acc = 0.f;
  #pragma unroll
  for (int k = 0; k < 5; ++k) {
    const float* pr = pstack + ((size_t)k * N_RES + r) * 128;
    const float* g  = G + (size_t)k * 16384;
    for (int j = 0; j < 128; ++j) acc += pr[j] * g[j * 128 + c];
  }
  if (c < D) out[(size_t)r * D + c] = acc;
}

extern "C" void kernel_launch(void* const* d_in, const int* in_sizes, int n_in,
                              void* d_out, int out_size, void* d_ws, size_t ws_size,
                              hipStream_t stream)
{
  (void)in_sizes; (void)n_in; (void)out_size; (void)ws_size;
  const float* atom_emb = (const float*)d_in[1];
  const int*   eidx     = (const int*)d_in[2];
  const int*   r2a      = (const int*)d_in[3];
  const float* lnW      = (const float*)d_in[4];
  const float* lnb      = (const float*)d_in[5];
  const float* Wl       = (const float*)d_in[6];
  const float* Wr       = (const float*)d_in[7];
  const float* bl       = (const float*)d_in[8];
  float* out = (float*)d_out;

  char* p = (char*)d_ws;
  auto alloc = [&](size_t b) { char* r = p; p += (b + 255) & ~(size_t)255; return r; };
  unsigned short* y0   = (unsigned short*)alloc((size_t)MPAD * DP * 2);   // 25.6 MB
  unsigned short* y1   = (unsigned short*)alloc((size_t)MPAD * DP * 2);   // 25.6 MB
  float* pstack = (float*)alloc((size_t)5 * N_RES * 128 * 4);             // 32 MB
  float* R      = (float*)alloc((size_t)4 * 2 * 16384 * 4);               // 512 KB
  float* Ga     = (float*)alloc((size_t)5 * 16384 * 4);                   // 320 KB
  float* Gb     = (float*)alloc((size_t)5 * 16384 * 4);                   // 320 KB
  int*   hist      = (int*)alloc((size_t)N_ATOMS * 4);
  int*   row_start = (int*)alloc((size_t)(N_ATOMS + 1) * 4);
  int*   cursor    = (int*)alloc((size_t)N_ATOMS * 4);
  float* invdeg    = (float*)alloc((size_t)N_ATOMS * 4);
  int*   srcs      = (int*)alloc((size_t)N_EDGES * 4);
  int*   bsum      = (int*)alloc((size_t)256 * 4);
  int*   res_start = (int*)alloc((size_t)(N_RES + 1) * 4);

  hipMemsetAsync(hist, 0, (size_t)N_ATOMS * 4, stream);

  // CSR build
  k_hist_edges<<<(N_EDGES + 255) / 256, 256, 0, stream>>>(eidx, hist);
  k_scan_part<<<NSCB, 256, 0, stream>>>(hist, bsum);
  k_scan_bsum<<<1, 256, 0, stream>>>(bsum, row_start + N_ATOMS);
  k_scan_final<<<NSCB, 256, 0, stream>>>(hist, bsum, row_start, cursor, invdeg);
  k_res_bounds<<<(N_RES + 1 + 255) / 256, 256, 0, stream>>>(r2a, res_start);
  k_fill<<<(N_EDGES + 255) / 256, 256, 0, stream>>>(eidx, cursor, srcs);

  // weight-product DP: M_k = G_k^{(4)}
  k_buildR<<<512, 256, 0, stream>>>(Wl, Wr, bl, R);
  k_ginit<<<64, 256, 0, stream>>>(Ga);
  float* gc = Ga; float* gn = Gb;
  for (int l = 1; l <= N_LAYERS; ++l) {
    k_mdp<<<(l + 1) * 4, 256, 0, stream>>>(
        gc, gn, R + (size_t)(l - 1) * 2 * 16384, R + ((size_t)(l - 1) * 2 + 1) * 16384, l);
    float* tmp = gc; gc = gn; gn = tmp;
  }
  // gc now holds M_0..M_4

  // y0 = proj (with constant column), then yk = A y_{k-1}; pool each
  k_proj<<<MPAD / 128, 256, 0, stream>>>(atom_emb, lnW, lnb, y0);
  k_pool128<<<(N_RES * 64) / 256, 256, 0, stream>>>(
      (const unsigned int*)y0, res_start, pstack);
  unsigned short* cur = y0;
  unsigned short* nxt = y1;
  for (int k = 1; k <= N_LAYERS; ++k) {
    k_agg<<<(N_ATOMS * 64) / 256, 256, 0, stream>>>(
        (const unsigned int*)cur, row_start, srcs, invdeg, (unsigned int*)nxt);
    k_pool128<<<(N_RES * 64) / 256, 256, 0, stream>>>(
        (const unsigned int*)nxt, res_start, pstack + (size_t)k * N_RES * 128);
    unsigned short* tmp = cur; cur = nxt; nxt = tmp;
  }

  k_final<<<(N_RES + 1) / 2, 256, 0, stream>>>(pstack, gc, out);
}

// Round 7
// 811.239 us; speedup vs baseline: 1.2217x; 1.2217x over previous
//
#include <hip/hip_runtime.h>
#include <hip/hip_bf16.h>

#define N_ATOMS 100000
#define N_RES   12500
#define N_EDGES 800000
#define D_IN    37
#define D       115
#define DP      128            // padded feature dim (bf16 row = 256 B)
#define MPAD    100096         // atoms padded to multiple of 128
#define N_LAYERS 4
#define SCE     1024           // elements per scan block (256 thr x 4)
#define NSCB    ((N_ATOMS + SCE - 1) / SCE)   // 98 scan blocks
#define KPROJ   64             // D_IN padded to MFMA K multiple
#define LSTRIDE 72             // proj LDS row stride (bf16)

typedef __bf16 bf16x8 __attribute__((ext_vector_type(8)));
typedef float  f32x4  __attribute__((ext_vector_type(4)));
typedef unsigned int u32x4 __attribute__((ext_vector_type(4)));

__device__ __forceinline__ unsigned short f2bf(float f) {
  unsigned u = __builtin_bit_cast(unsigned, f);
  u += 0x7fffu + ((u >> 16) & 1u);            // RNE
  return (unsigned short)(u >> 16);
}
__device__ __forceinline__ float bf2f(unsigned short h) {
  unsigned u = ((unsigned)h) << 16;
  return __builtin_bit_cast(float, u);
}
__device__ __forceinline__ bf16x8 ld_frag(const unsigned short* p) {
  u32x4 u = *reinterpret_cast<const u32x4*>(p);
  return __builtin_bit_cast(bf16x8, u);
}

// ---- CSR build -------------------------------------------------------------
__global__ void k_hist_edges(const int* __restrict__ eidx, int* __restrict__ hist) {
  int e = blockIdx.x * blockDim.x + threadIdx.x;
  if (e < N_EDGES) atomicAdd(&hist[eidx[N_EDGES + e]], 1);
}

__global__ __launch_bounds__(256) void k_scan_part(
    const int* __restrict__ cnt, int* __restrict__ bsum)
{
  __shared__ int sh[256];
  const int t = threadIdx.x, b = blockIdx.x;
  const int base = b * SCE + t * 4;
  int s = 0;
  #pragma unroll
  for (int i = 0; i < 4; ++i) { int id = base + i; if (id < N_ATOMS) s += cnt[id]; }
  sh[t] = s; __syncthreads();
  for (int d = 128; d > 0; d >>= 1) { if (t < d) sh[t] += sh[t + d]; __syncthreads(); }
  if (t == 0) bsum[b] = sh[0];
}
__global__ __launch_bounds__(256) void k_scan_bsum(
    int* __restrict__ bsum, int* __restrict__ total)
{
  __shared__ int sh[256];
  const int t = threadIdx.x;
  int v = (t < NSCB) ? bsum[t] : 0;
  sh[t] = v; __syncthreads();
  for (int d = 1; d < 256; d <<= 1) {
    int u = (t >= d) ? sh[t - d] : 0;
    __syncthreads();
    sh[t] += u;
    __syncthreads();
  }
  if (t < NSCB) bsum[t] = sh[t] - v;          // exclusive
  if (t == 255) *total = sh[255];
}
__global__ __launch_bounds__(256) void k_scan_final(
    const int* __restrict__ cnt, const int* __restrict__ bsum,
    int* __restrict__ offs, int* __restrict__ cursor, float* __restrict__ invdeg)
{
  __shared__ int sh[256];
  const int t = threadIdx.x, b = blockIdx.x;
  const int base = b * SCE + t * 4;
  int c[4]; int s = 0;
  #pragma unroll
  for (int i = 0; i < 4; ++i) {
    int id = base + i;
    c[i] = (id < N_ATOMS) ? cnt[id] : 0;
    s += c[i];
  }
  sh[t] = s; __syncthreads();
  for (int d = 1; d < 256; d <<= 1) {
    int u = (t >= d) ? sh[t - d] : 0;
    __syncthreads();
    sh[t] += u;
    __syncthreads();
  }
  int run = bsum[b] + sh[t] - s;
  #pragma unroll
  for (int i = 0; i < 4; ++i) {
    int id = base + i;
    if (id < N_ATOMS) {
      offs[id] = run;
      cursor[id] = run;
      invdeg[id] = 1.0f / (float)max(c[i], 1);
      run += c[i];
    }
  }
}

__global__ __launch_bounds__(256) void k_res_bounds(
    const int* __restrict__ r2a, int* __restrict__ res_start)
{
  int r = blockIdx.x * blockDim.x + threadIdx.x;
  if (r > N_RES) return;
  int lo = 0, hi = N_ATOMS;
  while (lo < hi) {
    int mid = (lo + hi) >> 1;
    if (r2a[mid] < r) lo = mid + 1; else hi = mid;
  }
  res_start[r] = lo;
}

__global__ void k_fill(const int* __restrict__ eidx, int* __restrict__ cursor,
                       int* __restrict__ srcs) {
  int e = blockIdx.x * blockDim.x + threadIdx.x;
  if (e < N_EDGES) {
    int s = eidx[e], d = eidx[N_EDGES + e];
    int pos = atomicAdd(&cursor[d], 1);
    srcs[pos] = s;
  }
}

// ---- init R (augmented right-multipliers) + G identity ---------------------
// R[l][side][128][128]: side0 = Rl (A-path, W^T), side1 = Rr (id-path, W^T + bias row + const)
__global__ void k_initRG(const float* __restrict__ Wl, const float* __restrict__ Wr,
                         const float* __restrict__ bl, float* __restrict__ R,
                         float* __restrict__ G)
{
  int idx = blockIdx.x * 256 + threadIdx.x;
  if (idx < 4 * 2 * 128 * 128) {
    int c = idx & 127, k = (idx >> 7) & 127, side = (idx >> 14) & 1, l = idx >> 15;
    float v = 0.f;
    if (side == 0) {
      if (k < D && c < D) v = Wl[(size_t)l * D * D + c * D + k];
    } else {
      if (k < D && c < D) v = Wr[(size_t)l * D * D + c * D + k];
      else if (k == D && c < D) v = bl[l * D + c];
      else if (k == D && c == D) v = 1.f;
    }
    R[idx] = v;
  } else {
    int g = idx - 4 * 2 * 128 * 128;
    if (g < 16384) G[g] = ((g >> 7) == (g & 127)) ? 1.f : 0.f;
  }
}

// ---- DP: G_k(l) = G_k(l-1) @ Rr_l + G_{k-1}(l-1) @ Rl_l --------------------
// grid = (lmax+1)*4; block b: k = b>>2, rows (b&3)*32..+32. Gp panels in LDS.
__global__ __launch_bounds__(256) void k_mdp(
    const float* __restrict__ Gp, float* __restrict__ Gn,
    const float* __restrict__ Rl, const float* __restrict__ Rr, int lmax)
{
  __shared__ float sA[32 * 130];
  __shared__ float sB[32 * 130];
  const int b = blockIdx.x;
  const int k = b >> 2;
  const int rbase = (b & 3) * 32;
  const int t = threadIdx.x;
  const bool vA = (k <= lmax - 1);   // Rr path uses Gp[k]
  const bool vB = (k >= 1);          // Rl path uses Gp[k-1]

  for (int idx = t; idx < 32 * 128; idx += 256) {
    const int r = idx >> 7, j = idx & 127;
    sA[r * 130 + j] = vA ? Gp[(size_t)k * 16384 + (rbase + r) * 128 + j] : 0.f;
    sB[r * 130 + j] = vB ? Gp[(size_t)(k - 1) * 16384 + (rbase + r) * 128 + j] : 0.f;
  }
  __syncthreads();

  const int lrow = t >> 3;           // 0..31
  const int c0 = (t & 7) * 16;
  float acc[16];
  #pragma unroll
  for (int q = 0; q < 16; ++q) acc[q] = 0.f;

  for (int j = 0; j < 128; ++j) {
    const float ga = sA[lrow * 130 + j];
    const float gb = sB[lrow * 130 + j];
    const f32x4* rr = reinterpret_cast<const f32x4*>(Rr + j * 128 + c0);
    const f32x4* rl = reinterpret_cast<const f32x4*>(Rl + j * 128 + c0);
    #pragma unroll
    for (int q4 = 0; q4 < 4; ++q4) {
      const f32x4 rv = rr[q4];
      const f32x4 lv = rl[q4];
      #pragma unroll
      for (int q = 0; q < 4; ++q)
        acc[q4 * 4 + q] += ga * rv[q] + gb * lv[q];
    }
  }
  float* o = Gn + (size_t)k * 16384 + (rbase + lrow) * 128 + c0;
  #pragma unroll
  for (int q = 0; q < 16; ++q) o[q] = acc[q];
}

// ---- input projection via MFMA: y0 = A @ lnW^T + lnb, bf16 [MPAD][128] -----
// col 115 = constant 1.0 (bias carrier), cols 116..127 = 0
__global__ __launch_bounds__(256) void k_proj(
    const float* __restrict__ A, const float* __restrict__ Wf,
    const float* __restrict__ bf, unsigned short* __restrict__ xout)
{
  __shared__ unsigned short sA[128 * LSTRIDE];
  __shared__ unsigned short sW[128 * LSTRIDE];
  const int t = threadIdx.x;
  const int r0 = blockIdx.x * 128;

  for (int idx = t; idx < 128 * KPROJ; idx += 256) {
    const int row = idx >> 6, k = idx & 63;
    const int gr = r0 + row;
    unsigned short v = 0;
    if (k < D_IN && gr < N_ATOMS) v = f2bf(A[(size_t)gr * D_IN + k]);
    sA[row * LSTRIDE + k] = v;
  }
  for (int idx = t; idx < 128 * KPROJ; idx += 256) {
    const int col = idx >> 6, k = idx & 63;
    unsigned short v = 0;
    if (col < D && k < D_IN) v = f2bf(Wf[col * D_IN + k]);
    sW[col * LSTRIDE + k] = v;
  }
  __syncthreads();

  const int lane = t & 63;
  const int wid  = t >> 6;
  const int wrow = wid * 32;
  const int lrow = lane & 15;
  const int koff = (lane >> 4) * 8;

  f32x4 acc[2][8];
  #pragma unroll
  for (int i = 0; i < 2; ++i)
    #pragma unroll
    for (int j = 0; j < 8; ++j)
      acc[i][j] = (f32x4){0.f, 0.f, 0.f, 0.f};

  #pragma unroll
  for (int ks = 0; ks < 2; ++ks) {
    const int k0 = ks * 32 + koff;
    bf16x8 a0 = ld_frag(&sA[(wrow + lrow) * LSTRIDE + k0]);
    bf16x8 a1 = ld_frag(&sA[(wrow + 16 + lrow) * LSTRIDE + k0]);
    #pragma unroll
    for (int ct = 0; ct < 8; ++ct) {
      bf16x8 b = ld_frag(&sW[(ct * 16 + lrow) * LSTRIDE + k0]);
      acc[0][ct] = __builtin_amdgcn_mfma_f32_16x16x32_bf16(a0, b, acc[0][ct], 0, 0, 0);
      acc[1][ct] = __builtin_amdgcn_mfma_f32_16x16x32_bf16(a1, b, acc[1][ct], 0, 0, 0);
    }
  }

  const int ocol = lane & 15;
  const int orow = (lane >> 4) * 4;
  #pragma unroll
  for (int ct = 0; ct < 8; ++ct) {
    const int col = ct * 16 + ocol;
    const float bv = (col < D) ? bf[col] : 0.f;
    #pragma unroll
    for (int rt = 0; rt < 2; ++rt) {
      #pragma unroll
      for (int j = 0; j < 4; ++j) {
        const int grow = r0 + wrow + rt * 16 + orow + j;
        if (grow < N_ATOMS) {
          unsigned short ov = (col == D) ? (unsigned short)0x3F80
                                         : f2bf(acc[rt][ct][j] + bv);
          xout[(size_t)grow * DP + col] = ov;
        }
      }
    }
  }
}

// ---- CSR mean aggregation: one wave/node, 4-edge-wide dwordx4 gather -------
// lane = (eg, ql): eg = lane>>4 edge-in-quad, ql = lane&15 feature chunk (8 bf16).
// One u32x4 load moves 4 edges' chunks simultaneously; shfl_xor 16/32 reduces.
__global__ __launch_bounds__(256) void k_agg(
    const unsigned int* __restrict__ xin, const int* __restrict__ row_start,
    const int* __restrict__ srcs, const float* __restrict__ invdeg,
    unsigned int* __restrict__ aggout)
{
  const int w = (int)((blockIdx.x * 256 + threadIdx.x) >> 6);
  const int lane = threadIdx.x & 63;
  if (w >= N_ATOMS) return;
  const int eg = lane >> 4, ql = lane & 15;
  const int beg = row_start[w], end = row_start[w + 1];
  float a[8] = {0.f,0.f,0.f,0.f,0.f,0.f,0.f,0.f};
  for (int base = beg; base < end; base += 16) {
    const int m = end - base;
    int sidx = 0;
    if (lane < 16 && lane < m) sidx = srcs[base + lane];
    #pragma unroll
    for (int b4 = 0; b4 < 4; ++b4) {
      const int j = b4 * 4 + eg;
      const int s = __shfl(sidx, j);
      if (j < m) {
        const u32x4 v = *(reinterpret_cast<const u32x4*>(xin + (size_t)s * 64) + ql);
        #pragma unroll
        for (int q = 0; q < 4; ++q) {
          a[2*q]   += bf2f((unsigned short)(v[q] & 0xffffu));
          a[2*q+1] += bf2f((unsigned short)(v[q] >> 16));
        }
      }
    }
  }
  #pragma unroll
  for (int q = 0; q < 8; ++q) {
    a[q] += __shfl_xor(a[q], 16);
    a[q] += __shfl_xor(a[q], 32);
  }
  if (lane < 16) {
    const float sc = invdeg[w];
    unsigned int pk[4];
    #pragma unroll
    for (int q = 0; q < 4; ++q)
      pk[q] = (unsigned int)f2bf(a[2*q] * sc) | ((unsigned int)f2bf(a[2*q+1] * sc) << 16);
    *(reinterpret_cast<u32x4*>(aggout + (size_t)w * 64) + ql) = (u32x4){pk[0],pk[1],pk[2],pk[3]};
  }
}

// ---- pooling into pstack slice: f32 [N_RES][128], 4-row-wide ---------------
__global__ __launch_bounds__(256) void k_pool128(
    const unsigned int* __restrict__ x, const int* __restrict__ res_start,
    float* __restrict__ outp)
{
  const int r = (int)((blockIdx.x * 256 + threadIdx.x) >> 6);
  const int lane = threadIdx.x & 63;
  if (r >= N_RES) return;
  const int eg = lane >> 4, ql = lane & 15;
  const int beg = res_start[r], end = res_start[r + 1];
  float a[8] = {0.f,0.f,0.f,0.f,0.f,0.f,0.f,0.f};
  for (int base = beg; base < end; base += 4) {
    const int row = base + eg;
    if (row < end) {
      const u32x4 v = *(reinterpret_cast<const u32x4*>(x + (size_t)row * 64) + ql);
      #pragma unroll
      for (int q = 0; q < 4; ++q) {
        a[2*q]   += bf2f((unsigned short)(v[q] & 0xffffu));
        a[2*q+1] += bf2f((unsigned short)(v[q] >> 16));
      }
    }
  }
  #pragma unroll
  for (int q = 0; q < 8; ++q) {
    a[q] += __shfl_xor(a[q], 16);
    a[q] += __shfl_xor(a[q], 32);
  }
  if (lane < 16) {
    f32x4* o = reinterpret_cast<f32x4*>(outp + (size_t)r * 128);
    o[ql * 2]     = (f32x4){a[0], a[1], a[2], a[3]};
    o[ql * 2 + 1] = (f32x4){a[4], a[5], a[6], a[7]};
  }
}

// ---- final GEMM: out[r][c] = sum_k pstack[k][r][:] @ G[k][:][c], c<115 -----
// 64 rows x 128 cols / block; thread = 4 rows x 8 cols; p-tile in LDS.
__global__ __launch_bounds__(256) void k_final(
    const float* __restrict__ pstack, const float* __restrict__ G,
    float* __restrict__ out)
{
  __shared__ float sp[64 * 130];
  const int t = threadIdx.x;
  const int r0 = blockIdx.x * 64;
  const int tr = t >> 4;         // 0..15 -> rows tr*4..+4
  const int c0 = (t & 15) * 8;

  float acc[4][8];
  #pragma unroll
  for (int i = 0; i < 4; ++i)
    #pragma unroll
    for (int j = 0; j < 8; ++j) acc[i][j] = 0.f;

  for (int k = 0; k < 5; ++k) {
    __syncthreads();
    for (int idx = t; idx < 64 * 128; idx += 256) {
      const int r = idx >> 7, j = idx & 127;
      sp[r * 130 + j] = (r0 + r < N_RES)
          ? pstack[((size_t)k * N_RES + r0 + r) * 128 + j] : 0.f;
    }
    __syncthreads();
    const float* g = G + (size_t)k * 16384;
    for (int j = 0; j < 128; ++j) {
      const f32x4 ga = *reinterpret_cast<const f32x4*>(g + j * 128 + c0);
      const f32x4 gb = *reinterpret_cast<const f32x4*>(g + j * 128 + c0 + 4);
      float pr[4];
      #pragma unroll
      for (int rr = 0; rr < 4; ++rr) pr[rr] = sp[(tr * 4 + rr) * 130 + j];
      #pragma unroll
      for (int rr = 0; rr < 4; ++rr) {
        #pragma unroll
        for (int q = 0; q < 4; ++q) {
          acc[rr][q]     += pr[rr] * ga[q];
          acc[rr][q + 4] += pr[rr] * gb[q];
        }
      }
    }
  }

  #pragma unroll
  for (int rr = 0; rr < 4; ++rr) {
    const int row = r0 + tr * 4 + rr;
    if (row < N_RES) {
      #pragma unroll
      for (int q = 0; q < 8; ++q) {
        const int col = c0 + q;
        if (col < D) out[(size_t)row * D + col] = acc[rr][q];
      }
    }
  }
}

extern "C" void kernel_launch(void* const* d_in, const int* in_sizes, int n_in,
                              void* d_out, int out_size, void* d_ws, size_t ws_size,
                              hipStream_t stream)
{
  (void)in_sizes; (void)n_in; (void)out_size; (void)ws_size;
  const float* atom_emb = (const float*)d_in[1];
  const int*   eidx     = (const int*)d_in[2];
  const int*   r2a      = (const int*)d_in[3];
  const float* lnW      = (const float*)d_in[4];
  const float* lnb      = (const float*)d_in[5];
  const float* Wl       = (const float*)d_in[6];
  const float* Wr       = (const float*)d_in[7];
  const float* bl       = (const float*)d_in[8];
  float* out = (float*)d_out;

  char* p = (char*)d_ws;
  auto alloc = [&](size_t b) { char* r = p; p += (b + 255) & ~(size_t)255; return r; };
  unsigned short* y0   = (unsigned short*)alloc((size_t)MPAD * DP * 2);
  unsigned short* y1   = (unsigned short*)alloc((size_t)MPAD * DP * 2);
  float* pstack = (float*)alloc((size_t)5 * N_RES * 128 * 4);
  float* R      = (float*)alloc((size_t)4 * 2 * 16384 * 4);
  float* Ga     = (float*)alloc((size_t)5 * 16384 * 4);
  float* Gb     = (float*)alloc((size_t)5 * 16384 * 4);
  int*   hist      = (int*)alloc((size_t)N_ATOMS * 4);
  int*   row_start = (int*)alloc((size_t)(N_ATOMS + 1) * 4);
  int*   cursor    = (int*)alloc((size_t)N_ATOMS * 4);
  float* invdeg    = (float*)alloc((size_t)N_ATOMS * 4);
  int*   srcs      = (int*)alloc((size_t)N_EDGES * 4);
  int*   bsum      = (int*)alloc((size_t)256 * 4);
  int*   res_start = (int*)alloc((size_t)(N_RES + 1) * 4);

  hipMemsetAsync(hist, 0, (size_t)N_ATOMS * 4, stream);

  // CSR build
  k_hist_edges<<<(N_EDGES + 255) / 256, 256, 0, stream>>>(eidx, hist);
  k_scan_part<<<NSCB, 256, 0, stream>>>(hist, bsum);
  k_scan_bsum<<<1, 256, 0, stream>>>(bsum, row_start + N_ATOMS);
  k_scan_final<<<NSCB, 256, 0, stream>>>(hist, bsum, row_start, cursor, invdeg);
  k_res_bounds<<<(N_RES + 1 + 255) / 256, 256, 0, stream>>>(r2a, res_start);
  k_fill<<<(N_EDGES + 255) / 256, 256, 0, stream>>>(eidx, cursor, srcs);

  // weight-product DP: M_k = G_k^{(4)}
  k_initRG<<<(4 * 2 * 16384 + 16384 + 255) / 256, 256, 0, stream>>>(Wl, Wr, bl, R, Ga);
  float* gc = Ga; float* gn = Gb;
  for (int l = 1; l <= N_LAYERS; ++l) {
    k_mdp<<<(l + 1) * 4, 256, 0, stream>>>(
        gc, gn, R + (size_t)(l - 1) * 2 * 16384, R + ((size_t)(l - 1) * 2 + 1) * 16384, l);
    float* tmp = gc; gc = gn; gn = tmp;
  }

  // y0 = proj (with constant column), then yk = A y_{k-1}; pool each
  k_proj<<<MPAD / 128, 256, 0, stream>>>(atom_emb, lnW, lnb, y0);
  k_pool128<<<(N_RES * 64) / 256, 256, 0, stream>>>(
      (const unsigned int*)y0, res_start, pstack);
  unsigned short* cur = y0;
  unsigned short* nxt = y1;
  for (int k = 1; k <= N_LAYERS; ++k) {
    k_agg<<<(N_ATOMS * 64) / 256, 256, 0, stream>>>(
        (const unsigned int*)cur, row_start, srcs, invdeg, (unsigned int*)nxt);
    k_pool128<<<(N_RES * 64) / 256, 256, 0, stream>>>(
        (const unsigned int*)nxt, res_start, pstack + (size_t)k * N_RES * 128);
    unsigned short* tmp = cur; cur = nxt; nxt = tmp;
  }

  k_final<<<(N_RES + 63) / 64, 256, 0, stream>>>(pstack, gc, out);
}

// Round 9
// 790.325 us; speedup vs baseline: 1.2541x; 1.0265x over previous
//
#include <hip/hip_runtime.h>
#include <hip/hip_bf16.h>

#define N_ATOMS 100000
#define N_RES   12500
#define N_EDGES 800000
#define D_IN    37
#define D       115
#define DP      128            // padded feature dim (bf16 row = 256 B)
#define MPAD    100096         // atoms padded to multiple of 128
#define N_LAYERS 4
#define SCE     1024           // elements per scan block (256 thr x 4)
#define NSCB    ((N_ATOMS + SCE - 1) / SCE)   // 98 scan blocks
#define KPROJ   64             // D_IN padded to MFMA K multiple
#define LSTRIDE 72             // proj LDS row stride (bf16)
#define FTILES  ((N_RES + 31) / 32)           // 391 row-tiles for final GEMM

typedef __bf16 bf16x8 __attribute__((ext_vector_type(8)));
typedef float  f32x4  __attribute__((ext_vector_type(4)));
typedef unsigned int u32x4 __attribute__((ext_vector_type(4)));

__device__ __forceinline__ unsigned short f2bf(float f) {
  unsigned u = __builtin_bit_cast(unsigned, f);
  u += 0x7fffu + ((u >> 16) & 1u);            // RNE
  return (unsigned short)(u >> 16);
}
__device__ __forceinline__ float bf2f(unsigned short h) {
  unsigned u = ((unsigned)h) << 16;
  return __builtin_bit_cast(float, u);
}
__device__ __forceinline__ bf16x8 ld_frag(const unsigned short* p) {
  u32x4 u = *reinterpret_cast<const u32x4*>(p);
  return __builtin_bit_cast(bf16x8, u);
}

// ---- CSR build -------------------------------------------------------------
__global__ void k_hist_edges(const int* __restrict__ eidx, int* __restrict__ hist) {
  int e = blockIdx.x * blockDim.x + threadIdx.x;
  if (e < N_EDGES) atomicAdd(&hist[eidx[N_EDGES + e]], 1);
}

__global__ __launch_bounds__(256) void k_scan_part(
    const int* __restrict__ cnt, int* __restrict__ bsum)
{
  __shared__ int sh[256];
  const int t = threadIdx.x, b = blockIdx.x;
  const int base = b * SCE + t * 4;
  int s = 0;
  #pragma unroll
  for (int i = 0; i < 4; ++i) { int id = base + i; if (id < N_ATOMS) s += cnt[id]; }
  sh[t] = s; __syncthreads();
  for (int d = 128; d > 0; d >>= 1) { if (t < d) sh[t] += sh[t + d]; __syncthreads(); }
  if (t == 0) bsum[b] = sh[0];
}
__global__ __launch_bounds__(256) void k_scan_bsum(
    int* __restrict__ bsum, int* __restrict__ total)
{
  __shared__ int sh[256];
  const int t = threadIdx.x;
  int v = (t < NSCB) ? bsum[t] : 0;
  sh[t] = v; __syncthreads();
  for (int d = 1; d < 256; d <<= 1) {
    int u = (t >= d) ? sh[t - d] : 0;
    __syncthreads();
    sh[t] += u;
    __syncthreads();
  }
  if (t < NSCB) bsum[t] = sh[t] - v;          // exclusive
  if (t == 255) *total = sh[255];
}
__global__ __launch_bounds__(256) void k_scan_final(
    const int* __restrict__ cnt, const int* __restrict__ bsum,
    int* __restrict__ offs, int* __restrict__ cursor, float* __restrict__ invdeg)
{
  __shared__ int sh[256];
  const int t = threadIdx.x, b = blockIdx.x;
  const int base = b * SCE + t * 4;
  int c[4]; int s = 0;
  #pragma unroll
  for (int i = 0; i < 4; ++i) {
    int id = base + i;
    c[i] = (id < N_ATOMS) ? cnt[id] : 0;
    s += c[i];
  }
  sh[t] = s; __syncthreads();
  for (int d = 1; d < 256; d <<= 1) {
    int u = (t >= d) ? sh[t - d] : 0;
    __syncthreads();
    sh[t] += u;
    __syncthreads();
  }
  int run = bsum[b] + sh[t] - s;
  #pragma unroll
  for (int i = 0; i < 4; ++i) {
    int id = base + i;
    if (id < N_ATOMS) {
      offs[id] = run;
      cursor[id] = run;
      invdeg[id] = 1.0f / (float)max(c[i], 1);
      run += c[i];
    }
  }
}

__global__ __launch_bounds__(256) void k_res_bounds(
    const int* __restrict__ r2a, int* __restrict__ res_start)
{
  int r = blockIdx.x * blockDim.x + threadIdx.x;
  if (r > N_RES) return;
  int lo = 0, hi = N_ATOMS;
  while (lo < hi) {
    int mid = (lo + hi) >> 1;
    if (r2a[mid] < r) lo = mid + 1; else hi = mid;
  }
  res_start[r] = lo;
}

__global__ void k_fill(const int* __restrict__ eidx, int* __restrict__ cursor,
                       int* __restrict__ srcs) {
  int e = blockIdx.x * blockDim.x + threadIdx.x;
  if (e < N_EDGES) {
    int s = eidx[e], d = eidx[N_EDGES + e];
    int pos = atomicAdd(&cursor[d], 1);
    srcs[pos] = s;
  }
}

// ---- init R (augmented right-multipliers) + G identity ---------------------
__global__ void k_initRG(const float* __restrict__ Wl, const float* __restrict__ Wr,
                         const float* __restrict__ bl, float* __restrict__ R,
                         float* __restrict__ G)
{
  int idx = blockIdx.x * 256 + threadIdx.x;
  if (idx < 4 * 2 * 128 * 128) {
    int c = idx & 127, k = (idx >> 7) & 127, side = (idx >> 14) & 1, l = idx >> 15;
    float v = 0.f;
    if (side == 0) {
      if (k < D && c < D) v = Wl[(size_t)l * D * D + c * D + k];
    } else {
      if (k < D && c < D) v = Wr[(size_t)l * D * D + c * D + k];
      else if (k == D && c < D) v = bl[l * D + c];
      else if (k == D && c == D) v = 1.f;
    }
    R[idx] = v;
  } else {
    int g = idx - 4 * 2 * 128 * 128;
    if (g < 16384) G[g] = ((g >> 7) == (g & 127)) ? 1.f : 0.f;
  }
}

// ---- DP: G_k(l) = G_k(l-1) @ Rr_l + G_{k-1}(l-1) @ Rl_l --------------------
__global__ __launch_bounds__(256) void k_mdp(
    const float* __restrict__ Gp, float* __restrict__ Gn,
    const float* __restrict__ Rl, const float* __restrict__ Rr, int lmax)
{
  __shared__ float sA[32 * 130];
  __shared__ float sB[32 * 130];
  const int b = blockIdx.x;
  const int k = b >> 2;
  const int rbase = (b & 3) * 32;
  const int t = threadIdx.x;
  const bool vA = (k <= lmax - 1);
  const bool vB = (k >= 1);

  for (int idx = t; idx < 32 * 128; idx += 256) {
    const int r = idx >> 7, j = idx & 127;
    sA[r * 130 + j] = vA ? Gp[(size_t)k * 16384 + (rbase + r) * 128 + j] : 0.f;
    sB[r * 130 + j] = vB ? Gp[(size_t)(k - 1) * 16384 + (rbase + r) * 128 + j] : 0.f;
  }
  __syncthreads();

  const int lrow = t >> 3;
  const int c0 = (t & 7) * 16;
  float acc[16];
  #pragma unroll
  for (int q = 0; q < 16; ++q) acc[q] = 0.f;

  for (int j = 0; j < 128; ++j) {
    const float ga = sA[lrow * 130 + j];
    const float gb = sB[lrow * 130 + j];
    const f32x4* rr = reinterpret_cast<const f32x4*>(Rr + j * 128 + c0);
    const f32x4* rl = reinterpret_cast<const f32x4*>(Rl + j * 128 + c0);
    #pragma unroll
    for (int q4 = 0; q4 < 4; ++q4) {
      const f32x4 rv = rr[q4];
      const f32x4 lv = rl[q4];
      #pragma unroll
      for (int q = 0; q < 4; ++q)
        acc[q4 * 4 + q] += ga * rv[q] + gb * lv[q];
    }
  }
  float* o = Gn + (size_t)k * 16384 + (rbase + lrow) * 128 + c0;
  #pragma unroll
  for (int q = 0; q < 16; ++q) o[q] = acc[q];
}

// ---- input projection via MFMA: y0 = A @ lnW^T + lnb, bf16 [MPAD][128] -----
// col 115 = constant 1.0 (bias carrier), cols 116..127 = 0
__global__ __launch_bounds__(256) void k_proj(
    const float* __restrict__ A, const float* __restrict__ Wf,
    const float* __restrict__ bf, unsigned short* __restrict__ xout)
{
  __shared__ unsigned short sA[128 * LSTRIDE];
  __shared__ unsigned short sW[128 * LSTRIDE];
  const int t = threadIdx.x;
  const int r0 = blockIdx.x * 128;

  for (int idx = t; idx < 128 * KPROJ; idx += 256) {
    const int row = idx >> 6, k = idx & 63;
    const int gr = r0 + row;
    unsigned short v = 0;
    if (k < D_IN && gr < N_ATOMS) v = f2bf(A[(size_t)gr * D_IN + k]);
    sA[row * LSTRIDE + k] = v;
  }
  for (int idx = t; idx < 128 * KPROJ; idx += 256) {
    const int col = idx >> 6, k = idx & 63;
    unsigned short v = 0;
    if (col < D && k < D_IN) v = f2bf(Wf[col * D_IN + k]);
    sW[col * LSTRIDE + k] = v;
  }
  __syncthreads();

  const int lane = t & 63;
  const int wid  = t >> 6;
  const int wrow = wid * 32;
  const int lrow = lane & 15;
  const int koff = (lane >> 4) * 8;

  f32x4 acc[2][8];
  #pragma unroll
  for (int i = 0; i < 2; ++i)
    #pragma unroll
    for (int j = 0; j < 8; ++j)
      acc[i][j] = (f32x4){0.f, 0.f, 0.f, 0.f};

  #pragma unroll
  for (int ks = 0; ks < 2; ++ks) {
    const int k0 = ks * 32 + koff;
    bf16x8 a0 = ld_frag(&sA[(wrow + lrow) * LSTRIDE + k0]);
    bf16x8 a1 = ld_frag(&sA[(wrow + 16 + lrow) * LSTRIDE + k0]);
    #pragma unroll
    for (int ct = 0; ct < 8; ++ct) {
      bf16x8 b = ld_frag(&sW[(ct * 16 + lrow) * LSTRIDE + k0]);
      acc[0][ct] = __builtin_amdgcn_mfma_f32_16x16x32_bf16(a0, b, acc[0][ct], 0, 0, 0);
      acc[1][ct] = __builtin_amdgcn_mfma_f32_16x16x32_bf16(a1, b, acc[1][ct], 0, 0, 0);
    }
  }

  const int ocol = lane & 15;
  const int orow = (lane >> 4) * 4;
  #pragma unroll
  for (int ct = 0; ct < 8; ++ct) {
    const int col = ct * 16 + ocol;
    const float bv = (col < D) ? bf[col] : 0.f;
    #pragma unroll
    for (int rt = 0; rt < 2; ++rt) {
      #pragma unroll
      for (int j = 0; j < 4; ++j) {
        const int grow = r0 + wrow + rt * 16 + orow + j;
        if (grow < N_ATOMS) {
          unsigned short ov = (col == D) ? (unsigned short)0x3F80
                                         : f2bf(acc[rt][ct][j] + bv);
          xout[(size_t)grow * DP + col] = ov;
        }
      }
    }
  }
}

// ---- CSR mean aggregation: one wave/node, 4-edge-wide dwordx4 gather -------
__global__ __launch_bounds__(256) void k_agg(
    const unsigned int* __restrict__ xin, const int* __restrict__ row_start,
    const int* __restrict__ srcs, const float* __restrict__ invdeg,
    unsigned int* __restrict__ aggout)
{
  const int w = (int)((blockIdx.x * 256 + threadIdx.x) >> 6);
  const int lane = threadIdx.x & 63;
  if (w >= N_ATOMS) return;
  const int eg = lane >> 4, ql = lane & 15;
  const int beg = row_start[w], end = row_start[w + 1];
  float a[8] = {0.f,0.f,0.f,0.f,0.f,0.f,0.f,0.f};
  for (int base = beg; base < end; base += 16) {
    const int m = end - base;
    int sidx = 0;
    if (lane < 16 && lane < m) sidx = srcs[base + lane];
    #pragma unroll
    for (int b4 = 0; b4 < 4; ++b4) {
      const int j = b4 * 4 + eg;
      const int s = __shfl(sidx, j);
      if (j < m) {
        const u32x4 v = *(reinterpret_cast<const u32x4*>(xin + (size_t)s * 64) + ql);
        #pragma unroll
        for (int q = 0; q < 4; ++q) {
          a[2*q]   += bf2f((unsigned short)(v[q] & 0xffffu));
          a[2*q+1] += bf2f((unsigned short)(v[q] >> 16));
        }
      }
    }
  }
  #pragma unroll
  for (int q = 0; q < 8; ++q) {
    a[q] += __shfl_xor(a[q], 16);
    a[q] += __shfl_xor(a[q], 32);
  }
  if (lane < 16) {
    const float sc = invdeg[w];
    unsigned int pk[4];
    #pragma unroll
    for (int q = 0; q < 4; ++q)
      pk[q] = (unsigned int)f2bf(a[2*q] * sc) | ((unsigned int)f2bf(a[2*q+1] * sc) << 16);
    *(reinterpret_cast<u32x4*>(aggout + (size_t)w * 64) + ql) = (u32x4){pk[0],pk[1],pk[2],pk[3]};
  }
}

// ---- pooling into pstack slice: f32 [N_RES][128], 4-row-wide ---------------
__global__ __launch_bounds__(256) void k_pool128(
    const unsigned int* __restrict__ x, const int* __restrict__ res_start,
    float* __restrict__ outp)
{
  const int r = (int)((blockIdx.x * 256 + threadIdx.x) >> 6);
  const int lane = threadIdx.x & 63;
  if (r >= N_RES) return;
  const int eg = lane >> 4, ql = lane & 15;
  const int beg = res_start[r], end = res_start[r + 1];
  float a[8] = {0.f,0.f,0.f,0.f,0.f,0.f,0.f,0.f};
  for (int base = beg; base < end; base += 4) {
    const int row = base + eg;
    if (row < end) {
      const u32x4 v = *(reinterpret_cast<const u32x4*>(x + (size_t)row * 64) + ql);
      #pragma unroll
      for (int q = 0; q < 4; ++q) {
        a[2*q]   += bf2f((unsigned short)(v[q] & 0xffffu));
        a[2*q+1] += bf2f((unsigned short)(v[q] >> 16));
      }
    }
  }
  #pragma unroll
  for (int q = 0; q < 8; ++q) {
    a[q] += __shfl_xor(a[q], 16);
    a[q] += __shfl_xor(a[q], 32);
  }
  if (lane < 16) {
    f32x4* o = reinterpret_cast<f32x4*>(outp + (size_t)r * 128);
    o[ql * 2]     = (f32x4){a[0], a[1], a[2], a[3]};
    o[ql * 2 + 1] = (f32x4){a[4], a[5], a[6], a[7]};
  }
}

// ---- final GEMM, k-split: partial[k] = pstack[k] @ G[k] --------------------
// grid = 5 * FTILES; block: 32 rows x 128 cols; thread = 2 rows x 8 cols.
// p-tile (16 KB) in LDS; G streamed from L2 (hot, 320 KB).
__global__ __launch_bounds__(256) void k_final_part(
    const float* __restrict__ pstack, const float* __restrict__ G,
    float* __restrict__ partial)
{
  __shared__ float sp[32 * 130];
  const int k    = blockIdx.x / FTILES;
  const int tile = blockIdx.x % FTILES;
  const int r0 = tile * 32;
  const int t = threadIdx.x;
  const int tr = t >> 4;         // 0..15 -> rows tr*2..+2
  const int c0 = (t & 15) * 8;

  for (int idx = t; idx < 32 * 128; idx += 256) {
    const int r = idx >> 7, j = idx & 127;
    sp[r * 130 + j] = (r0 + r < N_RES)
        ? pstack[((size_t)k * N_RES + r0 + r) * 128 + j] : 0.f;
  }
  __syncthreads();

  float acc[2][8];
  #pragma unroll
  for (int i = 0; i < 2; ++i)
    #pragma unroll
    for (int j = 0; j < 8; ++j) acc[i][j] = 0.f;

  const float* g = G + (size_t)k * 16384;
  #pragma unroll 2
  for (int j = 0; j < 128; ++j) {
    const f32x4 ga = *reinterpret_cast<const f32x4*>(g + j * 128 + c0);
    const f32x4 gb = *reinterpret_cast<const f32x4*>(g + j * 128 + c0 + 4);
    const float p0 = sp[(tr * 2) * 130 + j];
    const float p1 = sp[(tr * 2 + 1) * 130 + j];
    #pragma unroll
    for (int q = 0; q < 4; ++q) {
      acc[0][q]     += p0 * ga[q];
      acc[0][q + 4] += p0 * gb[q];
      acc[1][q]     += p1 * ga[q];
      acc[1][q + 4] += p1 * gb[q];
    }
  }

  #pragma unroll
  for (int rr = 0; rr < 2; ++rr) {
    const int row = r0 + tr * 2 + rr;
    if (row < N_RES) {
      float* o = partial + ((size_t)k * N_RES + row) * 128 + c0;
      #pragma unroll
      for (int q = 0; q < 4; ++q) o[q] = acc[rr][q];
      #pragma unroll
      for (int q = 0; q < 4; ++q) o[q + 4] = acc[rr][q + 4];
    }
  }
}

// ---- reduce 5 partials into out (c < 115) ----------------------------------
__global__ __launch_bounds__(256) void k_reduce5(
    const float* __restrict__ partial, float* __restrict__ out)
{
  const int idx = blockIdx.x * 256 + threadIdx.x;
  if (idx >= N_RES * 128) return;
  const int r = idx >> 7, c = idx & 127;
  float s = 0.f;
  #pragma unroll
  for (int k = 0; k < 5; ++k) s += partial[(size_t)k * N_RES * 128 + idx];
  if (c < D) out[(size_t)r * D + c] = s;
}

extern "C" void kernel_launch(void* const* d_in, const int* in_sizes, int n_in,
                              void* d_out, int out_size, void* d_ws, size_t ws_size,
                              hipStream_t stream)
{
  (void)in_sizes; (void)n_in; (void)out_size; (void)ws_size;
  const float* atom_emb = (const float*)d_in[1];
  const int*   eidx     = (const int*)d_in[2];
  const int*   r2a      = (const int*)d_in[3];
  const float* lnW      = (const float*)d_in[4];
  const float* lnb      = (const float*)d_in[5];
  const float* Wl       = (const float*)d_in[6];
  const float* Wr       = (const float*)d_in[7];
  const float* bl       = (const float*)d_in[8];
  float* out = (float*)d_out;

  char* p = (char*)d_ws;
  auto alloc = [&](size_t b) { char* r = p; p += (b + 255) & ~(size_t)255; return r; };
  unsigned short* y0   = (unsigned short*)alloc((size_t)MPAD * DP * 2);
  unsigned short* y1   = (unsigned short*)alloc((size_t)MPAD * DP * 2);
  float* pstack  = (float*)alloc((size_t)5 * N_RES * 128 * 4);
  float* partial = (float*)alloc((size_t)5 * N_RES * 128 * 4);
  float* R       = (float*)alloc((size_t)4 * 2 * 16384 * 4);
  float* Ga      = (float*)alloc((size_t)5 * 16384 * 4);
  float* Gb      = (float*)alloc((size_t)5 * 16384 * 4);
  int*   hist      = (int*)alloc((size_t)N_ATOMS * 4);
  int*   row_start = (int*)alloc((size_t)(N_ATOMS + 1) * 4);
  int*   cursor    = (int*)alloc((size_t)N_ATOMS * 4);
  float* invdeg    = (float*)alloc((size_t)N_ATOMS * 4);
  int*   srcs      = (int*)alloc((size_t)N_EDGES * 4);
  int*   bsum      = (int*)alloc((size_t)256 * 4);
  int*   res_start = (int*)alloc((size_t)(N_RES + 1) * 4);

  hipMemsetAsync(hist, 0, (size_t)N_ATOMS * 4, stream);

  // CSR build
  k_hist_edges<<<(N_EDGES + 255) / 256, 256, 0, stream>>>(eidx, hist);
  k_scan_part<<<NSCB, 256, 0, stream>>>(hist, bsum);
  k_scan_bsum<<<1, 256, 0, stream>>>(bsum, row_start + N_ATOMS);
  k_scan_final<<<NSCB, 256, 0, stream>>>(hist, bsum, row_start, cursor, invdeg);
  k_res_bounds<<<(N_RES + 1 + 255) / 256, 256, 0, stream>>>(r2a, res_start);
  k_fill<<<(N_EDGES + 255) / 256, 256, 0, stream>>>(eidx, cursor, srcs);

  // weight-product DP: M_k = G_k^{(4)}
  k_initRG<<<(4 * 2 * 16384 + 16384 + 255) / 256, 256, 0, stream>>>(Wl, Wr, bl, R, Ga);
  float* gc = Ga; float* gn = Gb;
  for (int l = 1; l <= N_LAYERS; ++l) {
    k_mdp<<<(l + 1) * 4, 256, 0, stream>>>(
        gc, gn, R + (size_t)(l - 1) * 2 * 16384, R + ((size_t)(l - 1) * 2 + 1) * 16384, l);
    float* tmp = gc; gc = gn; gn = tmp;
  }

  // y0 = proj (with constant column), then yk = A y_{k-1}; pool each
  k_proj<<<MPAD / 128, 256, 0, stream>>>(atom_emb, lnW, lnb, y0);
  k_pool128<<<(N_RES * 64) / 256, 256, 0, stream>>>(
      (const unsigned int*)y0, res_start, pstack);
  unsigned short* cur = y0;
  unsigned short* nxt = y1;
  for (int k = 1; k <= N_LAYERS; ++k) {
    k_agg<<<(N_ATOMS * 64) / 256, 256, 0, stream>>>(
        (const unsigned int*)cur, row_start, srcs, invdeg, (unsigned int*)nxt);
    k_pool128<<<(N_RES * 64) / 256, 256, 0, stream>>>(
        (const unsigned int*)nxt, res_start, pstack + (size_t)k * N_RES * 128);
    unsigned short* tmp = cur; cur = nxt; nxt = tmp;
  }

  k_final_part<<<5 * FTILES, 256, 0, stream>>>(pstack, gc, partial);
  k_reduce5<<<(N_RES * 128 + 255) / 256, 256, 0, stream>>>(partial, out);
}

// Round 10
// 760.911 us; speedup vs baseline: 1.3025x; 1.0387x over previous
//
#include <hip/hip_runtime.h>
#include <hip/hip_bf16.h>

#define N_ATOMS 100000
#define N_RES   12500
#define N_EDGES 800000
#define D_IN    37
#define D       115
#define DP      128            // padded feature dim (bf16 row = 256 B)
#define MPAD    100096         // atoms padded to multiple of 128
#define N_LAYERS 4
#define SCE     1024           // elements per scan block (256 thr x 4)
#define NSCB    ((N_ATOMS + SCE - 1) / SCE)   // 98 scan blocks
#define KPROJ   64             // D_IN padded to MFMA K multiple
#define LSTRIDE 72             // proj LDS row stride (bf16)
#define FTILES  ((N_RES + 31) / 32)           // 391 row-tiles for final GEMM
#define SPAD    36             // sp[j][r] row stride (144 B: 16B-aligned b128 reads)

typedef __bf16 bf16x8 __attribute__((ext_vector_type(8)));
typedef float  f32x4  __attribute__((ext_vector_type(4)));
typedef unsigned int u32x4 __attribute__((ext_vector_type(4)));

__device__ __forceinline__ unsigned short f2bf(float f) {
  unsigned u = __builtin_bit_cast(unsigned, f);
  u += 0x7fffu + ((u >> 16) & 1u);            // RNE
  return (unsigned short)(u >> 16);
}
__device__ __forceinline__ float bf2f(unsigned short h) {
  unsigned u = ((unsigned)h) << 16;
  return __builtin_bit_cast(float, u);
}
__device__ __forceinline__ bf16x8 ld_frag(const unsigned short* p) {
  u32x4 u = *reinterpret_cast<const u32x4*>(p);
  return __builtin_bit_cast(bf16x8, u);
}

// ---- CSR build -------------------------------------------------------------
__global__ void k_hist_edges(const int* __restrict__ eidx, int* __restrict__ hist) {
  int e = blockIdx.x * blockDim.x + threadIdx.x;
  if (e < N_EDGES) atomicAdd(&hist[eidx[N_EDGES + e]], 1);
}

__global__ __launch_bounds__(256) void k_scan_part(
    const int* __restrict__ cnt, int* __restrict__ bsum)
{
  __shared__ int sh[256];
  const int t = threadIdx.x, b = blockIdx.x;
  const int base = b * SCE + t * 4;
  int s = 0;
  #pragma unroll
  for (int i = 0; i < 4; ++i) { int id = base + i; if (id < N_ATOMS) s += cnt[id]; }
  sh[t] = s; __syncthreads();
  for (int d = 128; d > 0; d >>= 1) { if (t < d) sh[t] += sh[t + d]; __syncthreads(); }
  if (t == 0) bsum[b] = sh[0];
}
__global__ __launch_bounds__(256) void k_scan_bsum(
    int* __restrict__ bsum, int* __restrict__ total)
{
  __shared__ int sh[256];
  const int t = threadIdx.x;
  int v = (t < NSCB) ? bsum[t] : 0;
  sh[t] = v; __syncthreads();
  for (int d = 1; d < 256; d <<= 1) {
    int u = (t >= d) ? sh[t - d] : 0;
    __syncthreads();
    sh[t] += u;
    __syncthreads();
  }
  if (t < NSCB) bsum[t] = sh[t] - v;          // exclusive
  if (t == 255) *total = sh[255];
}
__global__ __launch_bounds__(256) void k_scan_final(
    const int* __restrict__ cnt, const int* __restrict__ bsum,
    int* __restrict__ offs, int* __restrict__ cursor, float* __restrict__ invdeg)
{
  __shared__ int sh[256];
  const int t = threadIdx.x, b = blockIdx.x;
  const int base = b * SCE + t * 4;
  int c[4]; int s = 0;
  #pragma unroll
  for (int i = 0; i < 4; ++i) {
    int id = base + i;
    c[i] = (id < N_ATOMS) ? cnt[id] : 0;
    s += c[i];
  }
  sh[t] = s; __syncthreads();
  for (int d = 1; d < 256; d <<= 1) {
    int u = (t >= d) ? sh[t - d] : 0;
    __syncthreads();
    sh[t] += u;
    __syncthreads();
  }
  int run = bsum[b] + sh[t] - s;
  #pragma unroll
  for (int i = 0; i < 4; ++i) {
    int id = base + i;
    if (id < N_ATOMS) {
      offs[id] = run;
      cursor[id] = run;
      invdeg[id] = 1.0f / (float)max(c[i], 1);
      run += c[i];
    }
  }
}

__global__ __launch_bounds__(256) void k_res_bounds(
    const int* __restrict__ r2a, int* __restrict__ res_start)
{
  int r = blockIdx.x * blockDim.x + threadIdx.x;
  if (r > N_RES) return;
  int lo = 0, hi = N_ATOMS;
  while (lo < hi) {
    int mid = (lo + hi) >> 1;
    if (r2a[mid] < r) lo = mid + 1; else hi = mid;
  }
  res_start[r] = lo;
}

__global__ void k_fill(const int* __restrict__ eidx, int* __restrict__ cursor,
                       int* __restrict__ srcs) {
  int e = blockIdx.x * blockDim.x + threadIdx.x;
  if (e < N_EDGES) {
    int s = eidx[e], d = eidx[N_EDGES + e];
    int pos = atomicAdd(&cursor[d], 1);
    srcs[pos] = s;
  }
}

// ---- init R (augmented right-multipliers) + G identity ---------------------
__global__ void k_initRG(const float* __restrict__ Wl, const float* __restrict__ Wr,
                         const float* __restrict__ bl, float* __restrict__ R,
                         float* __restrict__ G)
{
  int idx = blockIdx.x * 256 + threadIdx.x;
  if (idx < 4 * 2 * 128 * 128) {
    int c = idx & 127, k = (idx >> 7) & 127, side = (idx >> 14) & 1, l = idx >> 15;
    float v = 0.f;
    if (side == 0) {
      if (k < D && c < D) v = Wl[(size_t)l * D * D + c * D + k];
    } else {
      if (k < D && c < D) v = Wr[(size_t)l * D * D + c * D + k];
      else if (k == D && c < D) v = bl[l * D + c];
      else if (k == D && c == D) v = 1.f;
    }
    R[idx] = v;
  } else {
    int g = idx - 4 * 2 * 128 * 128;
    if (g < 16384) G[g] = ((g >> 7) == (g & 127)) ? 1.f : 0.f;
  }
}

// ---- DP: G_k(l) = G_k(l-1) @ Rr_l + G_{k-1}(l-1) @ Rl_l --------------------
__global__ __launch_bounds__(256) void k_mdp(
    const float* __restrict__ Gp, float* __restrict__ Gn,
    const float* __restrict__ Rl, const float* __restrict__ Rr, int lmax)
{
  __shared__ float sA[32 * 130];
  __shared__ float sB[32 * 130];
  const int b = blockIdx.x;
  const int k = b >> 2;
  const int rbase = (b & 3) * 32;
  const int t = threadIdx.x;
  const bool vA = (k <= lmax - 1);
  const bool vB = (k >= 1);

  for (int idx = t; idx < 32 * 128; idx += 256) {
    const int r = idx >> 7, j = idx & 127;
    sA[r * 130 + j] = vA ? Gp[(size_t)k * 16384 + (rbase + r) * 128 + j] : 0.f;
    sB[r * 130 + j] = vB ? Gp[(size_t)(k - 1) * 16384 + (rbase + r) * 128 + j] : 0.f;
  }
  __syncthreads();

  const int lrow = t >> 3;
  const int c0 = (t & 7) * 16;
  float acc[16];
  #pragma unroll
  for (int q = 0; q < 16; ++q) acc[q] = 0.f;

  for (int j = 0; j < 128; ++j) {
    const float ga = sA[lrow * 130 + j];
    const float gb = sB[lrow * 130 + j];
    const f32x4* rr = reinterpret_cast<const f32x4*>(Rr + j * 128 + c0);
    const f32x4* rl = reinterpret_cast<const f32x4*>(Rl + j * 128 + c0);
    #pragma unroll
    for (int q4 = 0; q4 < 4; ++q4) {
      const f32x4 rv = rr[q4];
      const f32x4 lv = rl[q4];
      #pragma unroll
      for (int q = 0; q < 4; ++q)
        acc[q4 * 4 + q] += ga * rv[q] + gb * lv[q];
    }
  }
  float* o = Gn + (size_t)k * 16384 + (rbase + lrow) * 128 + c0;
  #pragma unroll
  for (int q = 0; q < 16; ++q) o[q] = acc[q];
}

// ---- input projection via MFMA: y0 = A @ lnW^T + lnb, bf16 [MPAD][128] -----
// col 115 = constant 1.0 (bias carrier), cols 116..127 = 0
__global__ __launch_bounds__(256) void k_proj(
    const float* __restrict__ A, const float* __restrict__ Wf,
    const float* __restrict__ bf, unsigned short* __restrict__ xout)
{
  __shared__ unsigned short sA[128 * LSTRIDE];
  __shared__ unsigned short sW[128 * LSTRIDE];
  const int t = threadIdx.x;
  const int r0 = blockIdx.x * 128;

  for (int idx = t; idx < 128 * KPROJ; idx += 256) {
    const int row = idx >> 6, k = idx & 63;
    const int gr = r0 + row;
    unsigned short v = 0;
    if (k < D_IN && gr < N_ATOMS) v = f2bf(A[(size_t)gr * D_IN + k]);
    sA[row * LSTRIDE + k] = v;
  }
  for (int idx = t; idx < 128 * KPROJ; idx += 256) {
    const int col = idx >> 6, k = idx & 63;
    unsigned short v = 0;
    if (col < D && k < D_IN) v = f2bf(Wf[col * D_IN + k]);
    sW[col * LSTRIDE + k] = v;
  }
  __syncthreads();

  const int lane = t & 63;
  const int wid  = t >> 6;
  const int wrow = wid * 32;
  const int lrow = lane & 15;
  const int koff = (lane >> 4) * 8;

  f32x4 acc[2][8];
  #pragma unroll
  for (int i = 0; i < 2; ++i)
    #pragma unroll
    for (int j = 0; j < 8; ++j)
      acc[i][j] = (f32x4){0.f, 0.f, 0.f, 0.f};

  #pragma unroll
  for (int ks = 0; ks < 2; ++ks) {
    const int k0 = ks * 32 + koff;
    bf16x8 a0 = ld_frag(&sA[(wrow + lrow) * LSTRIDE + k0]);
    bf16x8 a1 = ld_frag(&sA[(wrow + 16 + lrow) * LSTRIDE + k0]);
    #pragma unroll
    for (int ct = 0; ct < 8; ++ct) {
      bf16x8 b = ld_frag(&sW[(ct * 16 + lrow) * LSTRIDE + k0]);
      acc[0][ct] = __builtin_amdgcn_mfma_f32_16x16x32_bf16(a0, b, acc[0][ct], 0, 0, 0);
      acc[1][ct] = __builtin_amdgcn_mfma_f32_16x16x32_bf16(a1, b, acc[1][ct], 0, 0, 0);
    }
  }

  const int ocol = lane & 15;
  const int orow = (lane >> 4) * 4;
  #pragma unroll
  for (int ct = 0; ct < 8; ++ct) {
    const int col = ct * 16 + ocol;
    const float bv = (col < D) ? bf[col] : 0.f;
    #pragma unroll
    for (int rt = 0; rt < 2; ++rt) {
      #pragma unroll
      for (int j = 0; j < 4; ++j) {
        const int grow = r0 + wrow + rt * 16 + orow + j;
        if (grow < N_ATOMS) {
          unsigned short ov = (col == D) ? (unsigned short)0x3F80
                                         : f2bf(acc[rt][ct][j] + bv);
          xout[(size_t)grow * DP + col] = ov;
        }
      }
    }
  }
}

// ---- CSR mean aggregation: one wave/node, 4-edge-wide dwordx4 gather -------
__global__ __launch_bounds__(256) void k_agg(
    const unsigned int* __restrict__ xin, const int* __restrict__ row_start,
    const int* __restrict__ srcs, const float* __restrict__ invdeg,
    unsigned int* __restrict__ aggout)
{
  const int w = (int)((blockIdx.x * 256 + threadIdx.x) >> 6);
  const int lane = threadIdx.x & 63;
  if (w >= N_ATOMS) return;
  const int eg = lane >> 4, ql = lane & 15;
  const int beg = row_start[w], end = row_start[w + 1];
  float a[8] = {0.f,0.f,0.f,0.f,0.f,0.f,0.f,0.f};
  for (int base = beg; base < end; base += 16) {
    const int m = end - base;
    int sidx = 0;
    if (lane < 16 && lane < m) sidx = srcs[base + lane];
    #pragma unroll
    for (int b4 = 0; b4 < 4; ++b4) {
      const int j = b4 * 4 + eg;
      const int s = __shfl(sidx, j);
      if (j < m) {
        const u32x4 v = *(reinterpret_cast<const u32x4*>(xin + (size_t)s * 64) + ql);
        #pragma unroll
        for (int q = 0; q < 4; ++q) {
          a[2*q]   += bf2f((unsigned short)(v[q] & 0xffffu));
          a[2*q+1] += bf2f((unsigned short)(v[q] >> 16));
        }
      }
    }
  }
  #pragma unroll
  for (int q = 0; q < 8; ++q) {
    a[q] += __shfl_xor(a[q], 16);
    a[q] += __shfl_xor(a[q], 32);
  }
  if (lane < 16) {
    const float sc = invdeg[w];
    unsigned int pk[4];
    #pragma unroll
    for (int q = 0; q < 4; ++q)
      pk[q] = (unsigned int)f2bf(a[2*q] * sc) | ((unsigned int)f2bf(a[2*q+1] * sc) << 16);
    *(reinterpret_cast<u32x4*>(aggout + (size_t)w * 64) + ql) = (u32x4){pk[0],pk[1],pk[2],pk[3]};
  }
}

// ---- pooling into pstack slice: f32 [N_RES][128], 4-row-wide ---------------
__global__ __launch_bounds__(256) void k_pool128(
    const unsigned int* __restrict__ x, const int* __restrict__ res_start,
    float* __restrict__ outp)
{
  const int r = (int)((blockIdx.x * 256 + threadIdx.x) >> 6);
  const int lane = threadIdx.x & 63;
  if (r >= N_RES) return;
  const int eg = lane >> 4, ql = lane & 15;
  const int beg = res_start[r], end = res_start[r + 1];
  float a[8] = {0.f,0.f,0.f,0.f,0.f,0.f,0.f,0.f};
  for (int base = beg; base < end; base += 4) {
    const int row = base + eg;
    if (row < end) {
      const u32x4 v = *(reinterpret_cast<const u32x4*>(x + (size_t)row * 64) + ql);
      #pragma unroll
      for (int q = 0; q < 4; ++q) {
        a[2*q]   += bf2f((unsigned short)(v[q] & 0xffffu));
        a[2*q+1] += bf2f((unsigned short)(v[q] >> 16));
      }
    }
  }
  #pragma unroll
  for (int q = 0; q < 8; ++q) {
    a[q] += __shfl_xor(a[q], 16);
    a[q] += __shfl_xor(a[q], 32);
  }
  if (lane < 16) {
    f32x4* o = reinterpret_cast<f32x4*>(outp + (size_t)r * 128);
    o[ql * 2]     = (f32x4){a[0], a[1], a[2], a[3]};
    o[ql * 2 + 1] = (f32x4){a[4], a[5], a[6], a[7]};
  }
}

// ---- final GEMM, k-split: partial[k] = pstack[k] @ G[k] --------------------
// grid = 5*FTILES; block: 32 rows x 128 cols; thread = 8 rows x 2 cols
// (tr = t>>6 row-group = one wave; c0 = (t&63)*2). Wave's G load = one
// coalesced 512 B float2 row-slice per j (4x L1 redundancy, was 16x).
// p-tile staged TRANSPOSED in LDS sp[j][r] (SPAD=36 -> b128 reads aligned,
// wave-broadcast = conflict-free).
__global__ __launch_bounds__(256) void k_final_part(
    const float* __restrict__ pstack, const float* __restrict__ G,
    float* __restrict__ partial)
{
  __shared__ float sp[128 * SPAD];   // 18.4 KB
  const int k    = blockIdx.x / FTILES;
  const int tile = blockIdx.x % FTILES;
  const int r0 = tile * 32;
  const int t = threadIdx.x;
  const int tr = t >> 6;             // row group 0..3 -> rows tr*8..+8
  const int c0 = (t & 63) * 2;       // col pair

  // stage transposed: read coalesced over j, write sp[j][r]
  for (int idx = t; idx < 32 * 128; idx += 256) {
    const int r = idx >> 7, j = idx & 127;
    sp[j * SPAD + r] = (r0 + r < N_RES)
        ? pstack[((size_t)k * N_RES + r0 + r) * 128 + j] : 0.f;
  }
  __syncthreads();

  float accx[8], accy[8];
  #pragma unroll
  for (int i = 0; i < 8; ++i) { accx[i] = 0.f; accy[i] = 0.f; }

  const float* g = G + (size_t)k * 16384 + c0;
  for (int j = 0; j < 128; ++j) {
    const float2 gv = *reinterpret_cast<const float2*>(g + j * 128);
    const f32x4 p0 = *reinterpret_cast<const f32x4*>(&sp[j * SPAD + tr * 8]);
    const f32x4 p1 = *reinterpret_cast<const f32x4*>(&sp[j * SPAD + tr * 8 + 4]);
    #pragma unroll
    for (int rr = 0; rr < 4; ++rr) {
      accx[rr]     += p0[rr] * gv.x;
      accy[rr]     += p0[rr] * gv.y;
      accx[rr + 4] += p1[rr] * gv.x;
      accy[rr + 4] += p1[rr] * gv.y;
    }
  }

  #pragma unroll
  for (int rr = 0; rr < 8; ++rr) {
    const int row = r0 + tr * 8 + rr;
    if (row < N_RES) {
      float2* o = reinterpret_cast<float2*>(partial + ((size_t)k * N_RES + row) * 128 + c0);
      *o = (float2){accx[rr], accy[rr]};
    }
  }
}

// ---- reduce 5 partials into out (c < 115) ----------------------------------
__global__ __launch_bounds__(256) void k_reduce5(
    const float* __restrict__ partial, float* __restrict__ out)
{
  const int idx = blockIdx.x * 256 + threadIdx.x;
  if (idx >= N_RES * 128) return;
  const int r = idx >> 7, c = idx & 127;
  float s = 0.f;
  #pragma unroll
  for (int k = 0; k < 5; ++k) s += partial[(size_t)k * N_RES * 128 + idx];
  if (c < D) out[(size_t)r * D + c] = s;
}

extern "C" void kernel_launch(void* const* d_in, const int* in_sizes, int n_in,
                              void* d_out, int out_size, void* d_ws, size_t ws_size,
                              hipStream_t stream)
{
  (void)in_sizes; (void)n_in; (void)out_size; (void)ws_size;
  const float* atom_emb = (const float*)d_in[1];
  const int*   eidx     = (const int*)d_in[2];
  const int*   r2a      = (const int*)d_in[3];
  const float* lnW      = (const float*)d_in[4];
  const float* lnb      = (const float*)d_in[5];
  const float* Wl       = (const float*)d_in[6];
  const float* Wr       = (const float*)d_in[7];
  const float* bl       = (const float*)d_in[8];
  float* out = (float*)d_out;

  char* p = (char*)d_ws;
  auto alloc = [&](size_t b) { char* r = p; p += (b + 255) & ~(size_t)255; return r; };
  unsigned short* y0   = (unsigned short*)alloc((size_t)MPAD * DP * 2);
  unsigned short* y1   = (unsigned short*)alloc((size_t)MPAD * DP * 2);
  float* pstack  = (float*)alloc((size_t)5 * N_RES * 128 * 4);
  float* partial = (float*)alloc((size_t)5 * N_RES * 128 * 4);
  float* R       = (float*)alloc((size_t)4 * 2 * 16384 * 4);
  float* Ga      = (float*)alloc((size_t)5 * 16384 * 4);
  float* Gb      = (float*)alloc((size_t)5 * 16384 * 4);
  int*   hist      = (int*)alloc((size_t)N_ATOMS * 4);
  int*   row_start = (int*)alloc((size_t)(N_ATOMS + 1) * 4);
  int*   cursor    = (int*)alloc((size_t)N_ATOMS * 4);
  float* invdeg    = (float*)alloc((size_t)N_ATOMS * 4);
  int*   srcs      = (int*)alloc((size_t)N_EDGES * 4);
  int*   bsum      = (int*)alloc((size_t)256 * 4);
  int*   res_start = (int*)alloc((size_t)(N_RES + 1) * 4);

  hipMemsetAsync(hist, 0, (size_t)N_ATOMS * 4, stream);

  // CSR build
  k_hist_edges<<<(N_EDGES + 255) / 256, 256, 0, stream>>>(eidx, hist);
  k_scan_part<<<NSCB, 256, 0, stream>>>(hist, bsum);
  k_scan_bsum<<<1, 256, 0, stream>>>(bsum, row_start + N_ATOMS);
  k_scan_final<<<NSCB, 256, 0, stream>>>(hist, bsum, row_start, cursor, invdeg);
  k_res_bounds<<<(N_RES + 1 + 255) / 256, 256, 0, stream>>>(r2a, res_start);
  k_fill<<<(N_EDGES + 255) / 256, 256, 0, stream>>>(eidx, cursor, srcs);

  // weight-product DP: M_k = G_k^{(4)}
  k_initRG<<<(4 * 2 * 16384 + 16384 + 255) / 256, 256, 0, stream>>>(Wl, Wr, bl, R, Ga);
  float* gc = Ga; float* gn = Gb;
  for (int l = 1; l <= N_LAYERS; ++l) {
    k_mdp<<<(l + 1) * 4, 256, 0, stream>>>(
        gc, gn, R + (size_t)(l - 1) * 2 * 16384, R + ((size_t)(l - 1) * 2 + 1) * 16384, l);
    float* tmp = gc; gc = gn; gn = tmp;
  }

  // y0 = proj (with constant column), then yk = A y_{k-1}; pool each
  k_proj<<<MPAD / 128, 256, 0, stream>>>(atom_emb, lnW, lnb, y0);
  k_pool128<<<(N_RES * 64) / 256, 256, 0, stream>>>(
      (const unsigned int*)y0, res_start, pstack);
  unsigned short* cur = y0;
  unsigned short* nxt = y1;
  for (int k = 1; k <= N_LAYERS; ++k) {
    k_agg<<<(N_ATOMS * 64) / 256, 256, 0, stream>>>(
        (const unsigned int*)cur, row_start, srcs, invdeg, (unsigned int*)nxt);
    k_pool128<<<(N_RES * 64) / 256, 256, 0, stream>>>(
        (const unsigned int*)nxt, res_start, pstack + (size_t)k * N_RES * 128);
    unsigned short* tmp = cur; cur = nxt; nxt = tmp;
  }

  k_final_part<<<5 * FTILES, 256, 0, stream>>>(pstack, gc, partial);
  k_reduce5<<<(N_RES * 128 + 255) / 256, 256, 0, stream>>>(partial, out);
}